// Round 12
// baseline (307.820 us; speedup 1.0000x reference)
//
#include <hip/hip_runtime.h>
#include <hip/hip_bf16.h>

typedef __attribute__((ext_vector_type(8))) short bf16x8;   // 8 bf16 in 4 VGPRs
typedef __attribute__((ext_vector_type(4))) float f32x4;
typedef unsigned short u16;
typedef unsigned int u32;

#define DEV __device__ __forceinline__

DEV float bf2f(u16 v) { u32 u = ((u32)v) << 16; return __builtin_bit_cast(float, u); }
DEV u16 f2bf(float f) {
    u32 u = __builtin_bit_cast(u32, f);
    u32 r = (u + 0x7FFFu + ((u >> 16) & 1u)) >> 16;
    return (u16)r;
}

DEV void gll16(const u16* g, u16* l) {
    __builtin_amdgcn_global_load_lds((const __attribute__((address_space(1))) void*)g,
                                     (__attribute__((address_space(3))) void*)l, 16, 0, 0);
}

#define WAIT_VM0()   asm volatile("s_waitcnt vmcnt(0)" ::: "memory")
#define WAIT_VM4()   asm volatile("s_waitcnt vmcnt(4)" ::: "memory")
#define WAIT_LGKM0() asm volatile("s_waitcnt lgkmcnt(0)" ::: "memory")
#define BAR()        __builtin_amdgcn_s_barrier()
#define BARF()       asm volatile("s_barrier" ::: "memory")   // barrier + compiler mem fence

// ---------------------------------------------------------------------------
// Dtype detect: bits[14:7] of u32 words clustered (bf16 exponent) vs uniform (fp32 mantissa)
// ---------------------------------------------------------------------------
__global__ void detect_kernel(const u32* __restrict__ x, int* __restrict__ flag) {
    __shared__ int cnt;
    if (threadIdx.x == 0) cnt = 0;
    __syncthreads();
    int c = 0;
    for (int i = threadIdx.x; i < 4096; i += 256) {
        u32 w = x[i];
        u32 e = (w >> 7) & 0xFF;
        c += (e >= 110 && e <= 132) ? 1 : 0;
    }
    atomicAdd(&cnt, c);
    __syncthreads();
    if (threadIdx.x == 0) *flag = (cnt * 2 > 4096) ? 1 : 0;   // 1 = bf16, 0 = fp32
}

__global__ void cvt_bf16_kernel(const void* __restrict__ in, u16* __restrict__ out,
                                int n8, const int* __restrict__ flag) {
    const int fl = *flag;
    int i = blockIdx.x * 256 + threadIdx.x;
    const int stride = gridDim.x * 256;
    if (fl) {
        const bf16x8* ip = (const bf16x8*)in;
        bf16x8* op = (bf16x8*)out;
        for (; i < n8; i += stride) op[i] = ip[i];
    } else {
        const float4* ip = (const float4*)in;
        bf16x8* op = (bf16x8*)out;
        for (; i < n8; i += stride) {
            float4 a = ip[2 * i], b = ip[2 * i + 1];
            bf16x8 o;
            o[0] = (short)f2bf(a.x); o[1] = (short)f2bf(a.y);
            o[2] = (short)f2bf(a.z); o[3] = (short)f2bf(a.w);
            o[4] = (short)f2bf(b.x); o[5] = (short)f2bf(b.y);
            o[6] = (short)f2bf(b.z); o[7] = (short)f2bf(b.w);
            op[i] = o;
        }
    }
}

__global__ void cvt_f32_kernel(const void* __restrict__ in, float* __restrict__ out,
                               int n, const int* __restrict__ flag) {
    const int fl = *flag;
    int i = blockIdx.x * 256 + threadIdx.x;
    if (i < n) out[i] = fl ? bf2f(((const u16*)in)[i]) : ((const float*)in)[i];
}

// ---------------------------------------------------------------------------
// RoPE cos/sin table: [768][512] float2
// ---------------------------------------------------------------------------
__global__ void rope_table_kernel(float2* __restrict__ tab) {
    int idx = blockIdx.x * 256 + threadIdx.x;
    int t = idx >> 9, j = idx & 511;
    float freq = expf(-(float)(2 * j) * (9.210340371976184f / 1024.0f)); // 10000^(-2j/1024)
    float ang = (float)t * freq;
    tab[idx] = make_float2(cosf(ang), sinf(ang));
}

// ---------------------------------------------------------------------------
// GEMM 256x256 tile, BK=32, 8 waves (2M x 4N), per-wave 128x64.
// 3-slot rotating LDS (96 KB) + 2 phases/tile + COUNTED vmcnt(4):
//   prologue: STAGE(0),STAGE(1); vmcnt(4) confirms STAGE(0); barrier
//   tile t: ph0 { read B+A-h0 frags; STAGE(t+2 -> (t+2)%3); bar; 16 MFMA; bar }
//           ph1 { read A-h1 frags; vmcnt(4) confirms STAGE(t+1); bar; 16 MFMA; bar }
// Loads stay in flight ~2 tiles; never drained mid-loop (tail only).
// Invariant: every wave confirms its own STAGE(t+1) before tile t's last
// barrier => after it, slot (t+1)%3 is globally ready. Slot (t+2)%3 was
// retired at tile t-1's last barrier (write-after-read safe).
// C[M][N] = A[M][K] @ W[N][K]^T + bias.  K hardcoded 1024 (NT=32 tiles).
// Swizzle: r8's counter-proven BK=32 involution (0 bank conflicts).
// ---------------------------------------------------------------------------
__global__ __launch_bounds__(512, 2)
void gemm256c_kernel(const u16* __restrict__ A, const u16* __restrict__ W,
                     const float* __restrict__ bias, void* __restrict__ C,
                     int N, const int* __restrict__ flag, int out_mode,
                     const float2* __restrict__ tab, int rope) {
    constexpr int K = 1024, NT = 32;
    __shared__ u16 lds[3][16384];   // 98304 B: per slot A[256][32] @0, B[256][32] @8192 u16
    const int tid = threadIdx.x;
    const int l = tid & 63, w = tid >> 6;
    const int wm = w >> 2, wn = w & 3;          // 2M x 4N wave grid
    const int lo = l & 15, hi = l >> 4;

    const int M0 = blockIdx.x * 256, N0 = blockIdx.y * 256;

    // staging: thread -> row rS=tid>>2 (0..127; +128 second call), chunk qS pre-swizzled
    const int rS = tid >> 2;
    const int qS = (tid & 3) ^ ((tid >> 3) & 3);
    const u16* Ag = A + (size_t)(M0 + rS) * K + qS * 8;
    const u16* Wg = W + (size_t)(N0 + rS) * K + qS * 8;
    const int lb = w * 512;                       // wave-uniform u16 base within call-group

    f32x4 acc[8][4] = {};

#define STAGE(kt, slot)                                                        \
    {                                                                          \
        u16* sA_ = &lds[slot][0];                                              \
        u16* sB_ = &lds[slot][8192];                                           \
        const u16* ga_ = Ag + (kt) * 32;                                       \
        const u16* gb_ = Wg + (kt) * 32;                                       \
        gll16(ga_,                   sA_ + lb);                                \
        gll16(ga_ + (size_t)128 * K, sA_ + 4096 + lb);                         \
        gll16(gb_,                   sB_ + lb);                                \
        gll16(gb_ + (size_t)128 * K, sB_ + 4096 + lb);                         \
    }

    STAGE(0, 0);
    STAGE(1, 1);
    WAIT_VM4();          // confirm own STAGE(0) before first barrier
    BARF();

    const int csw = (lo & 7) >> 1;               // f(row) for BK=32 swizzle

#pragma unroll 1
    for (int t = 0; t < NT; ++t) {
        const u16* sA = &lds[t % 3][0];
        const u16* sB = &lds[t % 3][8192];
        bf16x8 afr[4], bfr[4];

        // ---- phase 0: m-half 0 ----
#pragma unroll
        for (int n = 0; n < 4; ++n)
            bfr[n] = *(const bf16x8*)&sB[(wn * 64 + n * 16 + lo) * 32 + ((hi ^ csw) * 8)];
#pragma unroll
        for (int m = 0; m < 4; ++m)
            afr[m] = *(const bf16x8*)&sA[(wm * 128 + m * 16 + lo) * 32 + ((hi ^ csw) * 8)];
        if (t + 2 < NT) STAGE(t + 2, (t + 2) % 3);
        BARF();
        __builtin_amdgcn_s_setprio(1);
#pragma unroll
        for (int m = 0; m < 4; ++m)
#pragma unroll
            for (int n = 0; n < 4; ++n)
                acc[m][n] = __builtin_amdgcn_mfma_f32_16x16x32_bf16(afr[m], bfr[n], acc[m][n], 0, 0, 0);
        __builtin_amdgcn_s_setprio(0);
        BARF();

        // ---- phase 1: m-half 1 ----
#pragma unroll
        for (int m = 0; m < 4; ++m)
            afr[m] = *(const bf16x8*)&sA[(wm * 128 + 64 + m * 16 + lo) * 32 + ((hi ^ csw) * 8)];
        if (t + 1 < NT) {
            if (t + 2 < NT) { WAIT_VM4(); }      // confirms STAGE(t+1); STAGE(t+2) stays in flight
            else            { WAIT_VM0(); }      // tail: only STAGE(t+1) outstanding
        }
        BARF();
        __builtin_amdgcn_s_setprio(1);
#pragma unroll
        for (int m = 0; m < 4; ++m)
#pragma unroll
            for (int n = 0; n < 4; ++n)
                acc[4 + m][n] = __builtin_amdgcn_mfma_f32_16x16x32_bf16(afr[m], bfr[n], acc[4 + m][n], 0, 0, 0);
        __builtin_amdgcn_s_setprio(0);
        BARF();                                  // tile boundary: slot (t+1)%3 globally ready
    }
#undef STAGE

    // epilogue: C/D layout col=lane&15, row=(lane>>4)*4+j  [m89-verified]
    const int f32out = out_mode ? (*flag == 0) : 0;
    const int do_rope = rope && (N0 < 2048);
#pragma unroll
    for (int mi = 0; mi < 8; ++mi) {
        const int rbase = M0 + wm * 128 + (mi >> 2) * 64 + (mi & 3) * 16 + hi * 4;
        const int tbase = (M0 % 768) + wm * 128 + (mi >> 2) * 64 + (mi & 3) * 16 + hi * 4;
#pragma unroll
        for (int n = 0; n < 4; ++n) {
            const int col = N0 + wn * 64 + lo + n * 16;
            float bi = bias[col];
            const int jf = (col & 1023) >> 1;
            const int odd = col & 1;
#pragma unroll
            for (int j = 0; j < 4; ++j) {
                float v = acc[mi][n][j] + bi;
                if (do_rope) {
                    float partner = __shfl_xor(v, 1);   // adjacent column (lane lo^1)
                    float2 cs = tab[(tbase + j) * 512 + jf];
                    v = odd ? (v * cs.x + partner * cs.y) : (v * cs.x - partner * cs.y);
                }
                size_t idx = (size_t)(rbase + j) * N + col;
                if (f32out) ((float*)C)[idx] = v;
                else        ((u16*)C)[idx] = f2bf(v);
            }
        }
    }
}

// ---------------------------------------------------------------------------
// Flash attention, QBLK=128: block = (qt, h, b), 128 q-rows, 8 waves x 16 rows.
// (unchanged from passing round-11 version)
// ---------------------------------------------------------------------------
__global__ __launch_bounds__(512)
void attn_kernel(const u16* __restrict__ qkv, u16* __restrict__ y) {
    constexpr int T = 768, CH = 1024, QKVC = 3072;
    constexpr float NEG = -30000.0f;
    __shared__ u16 Ks[2][64 * 64];  // [key][d], cols XOR-swizzled by (key&7)*8
    __shared__ u16 Vt[64 * 72];     // [d][key], key-col XOR-swizzled by ((d>>3)&7)*8
    __shared__ u16 Ps[128 * 72];    // [q][key], stride-72

    const int tid = threadIdx.x, l = tid & 63, w = tid >> 6;   // w = 0..7
    const int qt = blockIdx.x, h = blockIdx.y, b = blockIdx.z;
    const int lo = l & 15, hi = l >> 4;
    const int kk = hi * 8;
    const int swzk = (lo & 7) * 8;

    const int qrow = qt * 128 + w * 16 + lo;
    const u16* qptr = qkv + (size_t)(b * T + qrow) * QKVC + h * 64 + kk;
    bf16x8 aq0r = *(const bf16x8*)qptr;
    bf16x8 aq1r = *(const bf16x8*)(qptr + 32);
    bf16x8 aq0, aq1;
#pragma unroll
    for (int e = 0; e < 8; ++e) {
        aq0[e] = (short)f2bf(bf2f((u16)aq0r[e]) * 0.125f);
        aq1[e] = (short)f2bf(bf2f((u16)aq1r[e]) * 0.125f);
    }

    f32x4 o[4] = {};
    float mrun[4] = {NEG, NEG, NEG, NEG};
    float lrun[4] = {0.f, 0.f, 0.f, 0.f};

    const int ksr = w * 8 + (l >> 3);
    const int ksc = ((l & 7) ^ ((l >> 3) & 7)) * 8;
    const u16* kbase = qkv + (size_t)(b * T + ksr) * QKVC + CH + h * 64 + ksc;

    const int vd0 = (tid & 7) * 8;
    const int vswz = (tid & 7) * 8;
    const int vr0 = tid >> 3;                    // 0..63
    const u16* vbase = qkv + (size_t)(b * T) * QKVC + 2 * CH + h * 64 + vd0;

    const int NTk = 2 * qt + 2;                  // K-tiles for this block

    gll16(kbase, &Ks[0][w * 512]);
    bf16x8 cv0 = *(const bf16x8*)(vbase + (size_t)vr0 * QKVC);
    WAIT_VM0();
#pragma unroll
    for (int e = 0; e < 8; ++e)
        Vt[(vd0 + e) * 72 + (vr0 ^ vswz)] = (u16)cv0[e];

    for (int kt = 0; kt < NTk; ++kt) {
        const int cur = kt & 1, nxt = cur ^ 1;
        bf16x8 nv0;
        if (kt + 1 < NTk) {
            const size_t koff = (size_t)((kt + 1) * 64) * QKVC;
            gll16(kbase + koff, &Ks[nxt][w * 512]);
            nv0 = *(const bf16x8*)(vbase + (size_t)((kt + 1) * 64 + vr0) * QKVC);
        }
        WAIT_LGKM0();
        BAR();

        __builtin_amdgcn_s_setprio(1);
        f32x4 s[4];
#pragma unroll
        for (int n = 0; n < 4; ++n) {
            bf16x8 kb0 = *(const bf16x8*)&Ks[cur][(n * 16 + lo) * 64 + (kk ^ swzk)];
            bf16x8 kb1 = *(const bf16x8*)&Ks[cur][(n * 16 + lo) * 64 + ((32 + kk) ^ swzk)];
            f32x4 z = {0.f, 0.f, 0.f, 0.f};
            z = __builtin_amdgcn_mfma_f32_16x16x32_bf16(aq0, kb0, z, 0, 0, 0);
            z = __builtin_amdgcn_mfma_f32_16x16x32_bf16(aq1, kb1, z, 0, 0, 0);
            s[n] = z;
        }
        __builtin_amdgcn_s_setprio(0);

        if (kt >= 2 * qt) {   // diagonal-crossing tiles only
#pragma unroll
            for (int n = 0; n < 4; ++n) {
                int kcol = kt * 64 + n * 16 + lo;
#pragma unroll
                for (int j = 0; j < 4; ++j)
                    if (kcol > qt * 128 + w * 16 + hi * 4 + j) s[n][j] = NEG;
            }
        }
        float mnew[4], corr[4];
#pragma unroll
        for (int j = 0; j < 4; ++j) {
            float mx = fmaxf(fmaxf(s[0][j], s[1][j]), fmaxf(s[2][j], s[3][j]));
            mx = fmaxf(mx, __shfl_xor(mx, 1));
            mx = fmaxf(mx, __shfl_xor(mx, 2));
            mx = fmaxf(mx, __shfl_xor(mx, 4));
            mx = fmaxf(mx, __shfl_xor(mx, 8));
            mnew[j] = fmaxf(mrun[j], mx);
            corr[j] = __expf(mrun[j] - mnew[j]);
            mrun[j] = mnew[j];
        }
        float p[4][4];
#pragma unroll
        for (int n = 0; n < 4; ++n)
#pragma unroll
            for (int j = 0; j < 4; ++j)
                p[n][j] = __expf(s[n][j] - mnew[j]);
#pragma unroll
        for (int j = 0; j < 4; ++j) {
            float r = p[0][j] + p[1][j] + p[2][j] + p[3][j];
            r += __shfl_xor(r, 1);
            r += __shfl_xor(r, 2);
            r += __shfl_xor(r, 4);
            r += __shfl_xor(r, 8);
            lrun[j] = lrun[j] * corr[j] + r;
        }
#pragma unroll
        for (int n = 0; n < 4; ++n)
#pragma unroll
            for (int j = 0; j < 4; ++j)
                o[n][j] *= corr[j];
#pragma unroll
        for (int n = 0; n < 4; ++n)
#pragma unroll
            for (int j = 0; j < 4; ++j)
                Ps[(w * 16 + hi * 4 + j) * 72 + n * 16 + lo] = f2bf(p[n][j]);

        __builtin_amdgcn_s_setprio(1);
#pragma unroll
        for (int c = 0; c < 2; ++c) {
            bf16x8 pa = *(const bf16x8*)&Ps[(w * 16 + lo) * 72 + c * 32 + kk];
#pragma unroll
            for (int n = 0; n < 4; ++n) {
                const int v = (n * 2 + (lo >> 3)) & 7;
                bf16x8 vb = *(const bf16x8*)&Vt[(n * 16 + lo) * 72 + ((c * 32 + kk) ^ (v * 8))];
                o[n] = __builtin_amdgcn_mfma_f32_16x16x32_bf16(pa, vb, o[n], 0, 0, 0);
            }
        }
        __builtin_amdgcn_s_setprio(0);

        if (kt + 1 < NTk) {
            WAIT_VM0();
            BAR();
#pragma unroll
            for (int e = 0; e < 8; ++e)
                Vt[(vd0 + e) * 72 + (vr0 ^ vswz)] = (u16)nv0[e];
        }
    }

    float inv[4];
#pragma unroll
    for (int j = 0; j < 4; ++j) inv[j] = (lrun[j] > 0.f) ? 1.0f / lrun[j] : 0.f;
#pragma unroll
    for (int n = 0; n < 4; ++n)
#pragma unroll
        for (int j = 0; j < 4; ++j) {
            int t = qt * 128 + w * 16 + hi * 4 + j;
            y[(size_t)(b * T + t) * CH + h * 64 + n * 16 + lo] = f2bf(o[n][j] * inv[j]);
        }
}

// ---------------------------------------------------------------------------
extern "C" void kernel_launch(void* const* d_in, const int* in_sizes, int n_in,
                              void* d_out, int out_size, void* d_ws, size_t ws_size,
                              hipStream_t stream) {
    char* ws = (char*)d_ws;
    int*   flag  = (int*)ws;
    u16*   xb    = (u16*)(ws + 256);
    u16*   Wqb   = (u16*)(ws + 256 + 25165824);
    u16*   Wob   = (u16*)(ws + 256 + 31457280);
    float* bqf   = (float*)(ws + 256 + 33554432);
    float* bof   = (float*)(ws + 256 + 33566720);
    u16*   qkv   = (u16*)(ws + 256 + 33570816);
    u16*   y     = (u16*)(ws + 256 + 109068288);
    float2* tab  = (float2*)(ws + 256 + 134234112);

    detect_kernel<<<1, 256, 0, stream>>>((const u32*)d_in[0], flag);
    cvt_bf16_kernel<<<2048, 256, 0, stream>>>(d_in[0], xb,  12582912 / 8, flag);
    cvt_bf16_kernel<<<1536, 256, 0, stream>>>(d_in[1], Wqb, 3145728 / 8, flag);
    cvt_bf16_kernel<<<512,  256, 0, stream>>>(d_in[3], Wob, 1048576 / 8, flag);
    cvt_f32_kernel<<<12, 256, 0, stream>>>(d_in[2], bqf, 3072, flag);
    cvt_f32_kernel<<<4,  256, 0, stream>>>(d_in[4], bof, 1024, flag);
    rope_table_kernel<<<768 * 512 / 256, 256, 0, stream>>>(tab);

    // QKV GEMM (M=12288, N=3072): 256x256 tiles, natural grid (48,12), fused bias+RoPE
    gemm256c_kernel<<<dim3(48, 12), 512, 0, stream>>>(xb, Wqb, bqf, qkv, 3072, flag, 0, tab, 1);
    // Attention: QBLK=128, grid (6, 16, 16), 512 threads
    attn_kernel<<<dim3(6, 16, 16), 512, 0, stream>>>(qkv, y);
    // Output GEMM (M=12288, N=1024): 256x256 tiles, natural grid (48,4)
    gemm256c_kernel<<<dim3(48, 4), 512, 0, stream>>>(y, Wob, bof, d_out, 1024, flag, 1, tab, 0);
}

// Round 13
// 290.997 us; speedup vs baseline: 1.0578x; 1.0578x over previous
//
#include <hip/hip_runtime.h>
#include <hip/hip_bf16.h>

typedef __attribute__((ext_vector_type(8))) short bf16x8;   // 8 bf16 in 4 VGPRs
typedef __attribute__((ext_vector_type(4))) float f32x4;
typedef unsigned short u16;
typedef unsigned int u32;

#define DEV __device__ __forceinline__

DEV float bf2f(u16 v) { u32 u = ((u32)v) << 16; return __builtin_bit_cast(float, u); }
DEV u16 f2bf(float f) {
    u32 u = __builtin_bit_cast(u32, f);
    u32 r = (u + 0x7FFFu + ((u >> 16) & 1u)) >> 16;
    return (u16)r;
}
DEV u16 f2bf_trunc(float f) { return (u16)(__builtin_bit_cast(u32, f) >> 16); }

DEV void gll16(const u16* g, u16* l) {
    __builtin_amdgcn_global_load_lds((const __attribute__((address_space(1))) void*)g,
                                     (__attribute__((address_space(3))) void*)l, 16, 0, 0);
}

#define WAIT_VM0()   asm volatile("s_waitcnt vmcnt(0)" ::: "memory")
#define WAIT_LGKM0() asm volatile("s_waitcnt lgkmcnt(0)" ::: "memory")
#define BAR()        __builtin_amdgcn_s_barrier()
#define BARF()       asm volatile("s_barrier" ::: "memory")   // barrier + compiler mem fence

// ---------------------------------------------------------------------------
// Dtype detect: bits[14:7] of u32 words clustered (bf16 exponent) vs uniform (fp32 mantissa)
// ---------------------------------------------------------------------------
__global__ void detect_kernel(const u32* __restrict__ x, int* __restrict__ flag) {
    __shared__ int cnt;
    if (threadIdx.x == 0) cnt = 0;
    __syncthreads();
    int c = 0;
    for (int i = threadIdx.x; i < 4096; i += 256) {
        u32 w = x[i];
        u32 e = (w >> 7) & 0xFF;
        c += (e >= 110 && e <= 132) ? 1 : 0;
    }
    atomicAdd(&cnt, c);
    __syncthreads();
    if (threadIdx.x == 0) *flag = (cnt * 2 > 4096) ? 1 : 0;   // 1 = bf16, 0 = fp32
}

__global__ void cvt_bf16_kernel(const void* __restrict__ in, u16* __restrict__ out,
                                int n8, const int* __restrict__ flag) {
    const int fl = *flag;
    int i = blockIdx.x * 256 + threadIdx.x;
    const int stride = gridDim.x * 256;
    if (fl) {
        const bf16x8* ip = (const bf16x8*)in;
        bf16x8* op = (bf16x8*)out;
        for (; i < n8; i += stride) op[i] = ip[i];
    } else {
        const float4* ip = (const float4*)in;
        bf16x8* op = (bf16x8*)out;
        for (; i < n8; i += stride) {
            float4 a = ip[2 * i], b = ip[2 * i + 1];
            bf16x8 o;
            o[0] = (short)f2bf(a.x); o[1] = (short)f2bf(a.y);
            o[2] = (short)f2bf(a.z); o[3] = (short)f2bf(a.w);
            o[4] = (short)f2bf(b.x); o[5] = (short)f2bf(b.y);
            o[6] = (short)f2bf(b.z); o[7] = (short)f2bf(b.w);
            op[i] = o;
        }
    }
}

// ---------------------------------------------------------------------------
// RoPE cos/sin table: [768][512] float2
// ---------------------------------------------------------------------------
__global__ void rope_table_kernel(float2* __restrict__ tab) {
    int idx = blockIdx.x * 256 + threadIdx.x;
    int t = idx >> 9, j = idx & 511;
    float freq = expf(-(float)(2 * j) * (9.210340371976184f / 1024.0f)); // 10000^(-2j/1024)
    float ang = (float)t * freq;
    tab[idx] = make_float2(cosf(ang), sinf(ang));
}

// ---------------------------------------------------------------------------
// GEMM 256x256 tile, BK=64, 8 waves (2M x 4N), per-wave 128x64, 2-buf LDS,
// 4 phases per K-tile (round-10-verified, best GEMM across 6 structures).
// bias read directly from raw input (bf16 or f32 per flag).
// ---------------------------------------------------------------------------
__global__ __launch_bounds__(512, 2)
void gemm256p_kernel(const u16* __restrict__ A, const u16* __restrict__ W,
                     const void* __restrict__ bias, void* __restrict__ C,
                     int N, const int* __restrict__ flag, int out_mode,
                     const float2* __restrict__ tab, int rope) {
    constexpr int K = 1024, NT = 16;
    __shared__ u16 lds[2][32768];   // 131072 B: per slot A @0 (32 KB), B @16384 u16
    const int tid = threadIdx.x;
    const int l = tid & 63, w = tid >> 6;
    const int wm = w >> 2, wn = w & 3;          // 2M x 4N wave grid
    const int lo = l & 15, hi = l >> 4;

    const int M0 = blockIdx.x * 256, N0 = blockIdx.y * 256;

    const int rS = tid >> 3;                      // 0..63
    const int qS = (tid & 7) ^ (rS & 7);
    const u16* Ag = A + (size_t)(M0 + rS) * K + qS * 8;
    const u16* Wg = W + (size_t)(N0 + rS) * K + qS * 8;
    const int lb = w * 512;                       // wave-uniform u16 base within call-group

    f32x4 acc[8][4] = {};

#define STG_A(kt, slot, half)                                                  \
    {                                                                          \
        u16* sA_ = &lds[slot][(half) * 8192];                                  \
        const u16* ga_ = Ag + (kt) * 64 + (size_t)(128 * (half)) * K;          \
        gll16(ga_,                  sA_ + lb);                                 \
        gll16(ga_ + (size_t)64 * K, sA_ + 4096 + lb);                          \
    }
#define STG_B(kt, slot, half)                                                  \
    {                                                                          \
        u16* sB_ = &lds[slot][16384 + (half) * 8192];                          \
        const u16* gb_ = Wg + (kt) * 64 + (size_t)(128 * (half)) * K;          \
        gll16(gb_,                  sB_ + lb);                                 \
        gll16(gb_ + (size_t)64 * K, sB_ + 4096 + lb);                          \
    }

    STG_A(0, 0, 0); STG_A(0, 0, 1);
    STG_B(0, 0, 0); STG_B(0, 0, 1);
    WAIT_VM0();
    BARF();

    const int csw = lo & 7;

#pragma unroll 1
    for (int t = 0; t < NT; ++t) {
        const int cur = t & 1, nxt = cur ^ 1;
        const u16* sA = &lds[cur][0];
        const u16* sB = &lds[cur][16384];
        bf16x8 afr[4], bfr[4];

        // ---- phase 0: ks=0, m-half 0 ----
#pragma unroll
        for (int n = 0; n < 4; ++n)
            bfr[n] = *(const bf16x8*)&sB[(wn * 64 + n * 16 + lo) * 64 + ((hi ^ csw) * 8)];
#pragma unroll
        for (int m = 0; m < 4; ++m)
            afr[m] = *(const bf16x8*)&sA[(wm * 128 + m * 16 + lo) * 64 + ((hi ^ csw) * 8)];
        if (t + 1 < NT) { STG_A(t + 1, nxt, 0); STG_A(t + 1, nxt, 1); }
        BARF();
        __builtin_amdgcn_s_setprio(1);
#pragma unroll
        for (int m = 0; m < 4; ++m)
#pragma unroll
            for (int n = 0; n < 4; ++n)
                acc[m][n] = __builtin_amdgcn_mfma_f32_16x16x32_bf16(afr[m], bfr[n], acc[m][n], 0, 0, 0);
        __builtin_amdgcn_s_setprio(0);
        BARF();

        // ---- phase 1: ks=0, m-half 1 ----
#pragma unroll
        for (int m = 0; m < 4; ++m)
            afr[m] = *(const bf16x8*)&sA[(wm * 128 + 64 + m * 16 + lo) * 64 + ((hi ^ csw) * 8)];
        if (t + 1 < NT) { STG_B(t + 1, nxt, 0); STG_B(t + 1, nxt, 1); }
        BARF();
        __builtin_amdgcn_s_setprio(1);
#pragma unroll
        for (int m = 0; m < 4; ++m)
#pragma unroll
            for (int n = 0; n < 4; ++n)
                acc[4 + m][n] = __builtin_amdgcn_mfma_f32_16x16x32_bf16(afr[m], bfr[n], acc[4 + m][n], 0, 0, 0);
        __builtin_amdgcn_s_setprio(0);
        BARF();

        // ---- phase 2: ks=1, m-half 0 ----
#pragma unroll
        for (int n = 0; n < 4; ++n)
            bfr[n] = *(const bf16x8*)&sB[(wn * 64 + n * 16 + lo) * 64 + (((4 + hi) ^ csw) * 8)];
#pragma unroll
        for (int m = 0; m < 4; ++m)
            afr[m] = *(const bf16x8*)&sA[(wm * 128 + m * 16 + lo) * 64 + (((4 + hi) ^ csw) * 8)];
        BARF();
        __builtin_amdgcn_s_setprio(1);
#pragma unroll
        for (int m = 0; m < 4; ++m)
#pragma unroll
            for (int n = 0; n < 4; ++n)
                acc[m][n] = __builtin_amdgcn_mfma_f32_16x16x32_bf16(afr[m], bfr[n], acc[m][n], 0, 0, 0);
        __builtin_amdgcn_s_setprio(0);
        BARF();

        // ---- phase 3: ks=1, m-half 1 ----
#pragma unroll
        for (int m = 0; m < 4; ++m)
            afr[m] = *(const bf16x8*)&sA[(wm * 128 + 64 + m * 16 + lo) * 64 + (((4 + hi) ^ csw) * 8)];
        WAIT_VM0();                              // own 8 stage loads (issued ph0/ph1) confirmed
        BARF();
        __builtin_amdgcn_s_setprio(1);
#pragma unroll
        for (int m = 0; m < 4; ++m)
#pragma unroll
            for (int n = 0; n < 4; ++n)
                acc[4 + m][n] = __builtin_amdgcn_mfma_f32_16x16x32_bf16(afr[m], bfr[n], acc[4 + m][n], 0, 0, 0);
        __builtin_amdgcn_s_setprio(0);
        BARF();                                  // tile boundary: buf[nxt] globally ready
    }
#undef STG_A
#undef STG_B

    // epilogue: C/D layout col=lane&15, row=(lane>>4)*4+j  [m89-verified]
    const int fl = *flag;
    const int f32out = out_mode ? (fl == 0) : 0;
    const int do_rope = rope && (N0 < 2048);
#pragma unroll
    for (int mi = 0; mi < 8; ++mi) {
        const int rbase = M0 + wm * 128 + (mi >> 2) * 64 + (mi & 3) * 16 + hi * 4;
        const int tbase = (M0 % 768) + wm * 128 + (mi >> 2) * 64 + (mi & 3) * 16 + hi * 4;
#pragma unroll
        for (int n = 0; n < 4; ++n) {
            const int col = N0 + wn * 64 + lo + n * 16;
            float bi = fl ? bf2f(((const u16*)bias)[col]) : ((const float*)bias)[col];
            const int jf = (col & 1023) >> 1;
            const int odd = col & 1;
#pragma unroll
            for (int j = 0; j < 4; ++j) {
                float v = acc[mi][n][j] + bi;
                if (do_rope) {
                    float partner = __shfl_xor(v, 1);   // adjacent column (lane lo^1)
                    float2 cs = tab[(tbase + j) * 512 + jf];
                    v = odd ? (v * cs.x + partner * cs.y) : (v * cs.x - partner * cs.y);
                }
                size_t idx = (size_t)(rbase + j) * N + col;
                if (f32out) ((float*)C)[idx] = v;
                else        ((u16*)C)[idx] = f2bf(v);
            }
        }
    }
}

// ---------------------------------------------------------------------------
// Flash attention, QBLK=128, 8 waves x 16 rows (r11-verified sync structure).
// VALU cuts: defer-max (THR=8, wave-uniform), deferred l-reduction (epilogue),
// truncating bf16 pack for P.
// ---------------------------------------------------------------------------
__global__ __launch_bounds__(512)
void attn_kernel(const u16* __restrict__ qkv, u16* __restrict__ y) {
    constexpr int T = 768, CH = 1024, QKVC = 3072;
    constexpr float NEG = -30000.0f;
    __shared__ u16 Ks[2][64 * 64];  // [key][d], cols XOR-swizzled by (key&7)*8
    __shared__ u16 Vt[64 * 72];     // [d][key], key-col XOR-swizzled by ((d>>3)&7)*8
    __shared__ u16 Ps[128 * 72];    // [q][key], stride-72

    const int tid = threadIdx.x, l = tid & 63, w = tid >> 6;   // w = 0..7
    const int qt = blockIdx.x, h = blockIdx.y, b = blockIdx.z;
    const int lo = l & 15, hi = l >> 4;
    const int kk = hi * 8;
    const int swzk = (lo & 7) * 8;

    const int qrow = qt * 128 + w * 16 + lo;
    const u16* qptr = qkv + (size_t)(b * T + qrow) * QKVC + h * 64 + kk;
    bf16x8 aq0r = *(const bf16x8*)qptr;
    bf16x8 aq1r = *(const bf16x8*)(qptr + 32);
    bf16x8 aq0, aq1;
#pragma unroll
    for (int e = 0; e < 8; ++e) {
        aq0[e] = (short)f2bf(bf2f((u16)aq0r[e]) * 0.125f);
        aq1[e] = (short)f2bf(bf2f((u16)aq1r[e]) * 0.125f);
    }

    f32x4 o[4] = {};
    float mrun[4] = {NEG, NEG, NEG, NEG};
    float lrun[4] = {0.f, 0.f, 0.f, 0.f};    // per-lane PARTIAL row-sums (reduced in epilogue)

    const int ksr = w * 8 + (l >> 3);
    const int ksc = ((l & 7) ^ ((l >> 3) & 7)) * 8;
    const u16* kbase = qkv + (size_t)(b * T + ksr) * QKVC + CH + h * 64 + ksc;

    const int vd0 = (tid & 7) * 8;
    const int vswz = (tid & 7) * 8;
    const int vr0 = tid >> 3;                    // 0..63
    const u16* vbase = qkv + (size_t)(b * T) * QKVC + 2 * CH + h * 64 + vd0;

    const int NTk = 2 * qt + 2;                  // K-tiles for this block

    gll16(kbase, &Ks[0][w * 512]);
    bf16x8 cv0 = *(const bf16x8*)(vbase + (size_t)vr0 * QKVC);
    WAIT_VM0();
#pragma unroll
    for (int e = 0; e < 8; ++e)
        Vt[(vd0 + e) * 72 + (vr0 ^ vswz)] = (u16)cv0[e];

    for (int kt = 0; kt < NTk; ++kt) {
        const int cur = kt & 1, nxt = cur ^ 1;
        bf16x8 nv0;
        if (kt + 1 < NTk) {
            const size_t koff = (size_t)((kt + 1) * 64) * QKVC;
            gll16(kbase + koff, &Ks[nxt][w * 512]);
            nv0 = *(const bf16x8*)(vbase + (size_t)((kt + 1) * 64 + vr0) * QKVC);
        }
        WAIT_LGKM0();
        BAR();

        __builtin_amdgcn_s_setprio(1);
        f32x4 s[4];
#pragma unroll
        for (int n = 0; n < 4; ++n) {
            bf16x8 kb0 = *(const bf16x8*)&Ks[cur][(n * 16 + lo) * 64 + (kk ^ swzk)];
            bf16x8 kb1 = *(const bf16x8*)&Ks[cur][(n * 16 + lo) * 64 + ((32 + kk) ^ swzk)];
            f32x4 z = {0.f, 0.f, 0.f, 0.f};
            z = __builtin_amdgcn_mfma_f32_16x16x32_bf16(aq0, kb0, z, 0, 0, 0);
            z = __builtin_amdgcn_mfma_f32_16x16x32_bf16(aq1, kb1, z, 0, 0, 0);
            s[n] = z;
        }
        __builtin_amdgcn_s_setprio(0);

        if (kt >= 2 * qt) {   // diagonal-crossing tiles only
#pragma unroll
            for (int n = 0; n < 4; ++n) {
                int kcol = kt * 64 + n * 16 + lo;
#pragma unroll
                for (int j = 0; j < 4; ++j)
                    if (kcol > qt * 128 + w * 16 + hi * 4 + j) s[n][j] = NEG;
            }
        }
        // tile max per row
        float mx[4];
#pragma unroll
        for (int j = 0; j < 4; ++j) {
            float m0 = fmaxf(fmaxf(s[0][j], s[1][j]), fmaxf(s[2][j], s[3][j]));
            m0 = fmaxf(m0, __shfl_xor(m0, 1));
            m0 = fmaxf(m0, __shfl_xor(m0, 2));
            m0 = fmaxf(m0, __shfl_xor(m0, 4));
            m0 = fmaxf(m0, __shfl_xor(m0, 8));
            mx[j] = m0;
        }
        // defer-max: rescale only when some row grows by > 8
        float g = fmaxf(fmaxf(mx[0] - mrun[0], mx[1] - mrun[1]),
                        fmaxf(mx[2] - mrun[2], mx[3] - mrun[3]));
        if (!__all(g <= 8.0f)) {
#pragma unroll
            for (int j = 0; j < 4; ++j) {
                float mn = fmaxf(mrun[j], mx[j]);
                float c = __expf(mrun[j] - mn);
                mrun[j] = mn;
                lrun[j] *= c;
#pragma unroll
                for (int n = 0; n < 4; ++n) o[n][j] *= c;
            }
        }
        float p[4][4];
#pragma unroll
        for (int n = 0; n < 4; ++n)
#pragma unroll
            for (int j = 0; j < 4; ++j) {
                p[n][j] = __expf(s[n][j] - mrun[j]);
                Ps[(w * 16 + hi * 4 + j) * 72 + n * 16 + lo] = f2bf_trunc(p[n][j]);
            }
#pragma unroll
        for (int j = 0; j < 4; ++j)
            lrun[j] += p[0][j] + p[1][j] + p[2][j] + p[3][j];   // per-lane partial

        __builtin_amdgcn_s_setprio(1);
#pragma unroll
        for (int c = 0; c < 2; ++c) {
            bf16x8 pa = *(const bf16x8*)&Ps[(w * 16 + lo) * 72 + c * 32 + kk];
#pragma unroll
            for (int n = 0; n < 4; ++n) {
                const int v = (n * 2 + (lo >> 3)) & 7;
                bf16x8 vb = *(const bf16x8*)&Vt[(n * 16 + lo) * 72 + ((c * 32 + kk) ^ (v * 8))];
                o[n] = __builtin_amdgcn_mfma_f32_16x16x32_bf16(pa, vb, o[n], 0, 0, 0);
            }
        }
        __builtin_amdgcn_s_setprio(0);

        if (kt + 1 < NTk) {
            WAIT_VM0();
            BAR();
#pragma unroll
            for (int e = 0; e < 8; ++e)
                Vt[(vd0 + e) * 72 + (vr0 ^ vswz)] = (u16)nv0[e];
        }
    }

    // epilogue: reduce partial row-sums across the 16-lane row group, normalize
    float inv[4];
#pragma unroll
    for (int j = 0; j < 4; ++j) {
        float r = lrun[j];
        r += __shfl_xor(r, 1);
        r += __shfl_xor(r, 2);
        r += __shfl_xor(r, 4);
        r += __shfl_xor(r, 8);
        inv[j] = (r > 0.f) ? 1.0f / r : 0.f;
    }
#pragma unroll
    for (int n = 0; n < 4; ++n)
#pragma unroll
        for (int j = 0; j < 4; ++j) {
            int t = qt * 128 + w * 16 + hi * 4 + j;
            y[(size_t)(b * T + t) * CH + h * 64 + n * 16 + lo] = f2bf(o[n][j] * inv[j]);
        }
}

// ---------------------------------------------------------------------------
extern "C" void kernel_launch(void* const* d_in, const int* in_sizes, int n_in,
                              void* d_out, int out_size, void* d_ws, size_t ws_size,
                              hipStream_t stream) {
    char* ws = (char*)d_ws;
    int*   flag  = (int*)ws;
    u16*   xb    = (u16*)(ws + 256);
    u16*   Wqb   = (u16*)(ws + 256 + 25165824);
    u16*   Wob   = (u16*)(ws + 256 + 31457280);
    u16*   qkv   = (u16*)(ws + 256 + 33570816);
    u16*   y     = (u16*)(ws + 256 + 109068288);
    float2* tab  = (float2*)(ws + 256 + 134234112);

    detect_kernel<<<1, 256, 0, stream>>>((const u32*)d_in[0], flag);
    cvt_bf16_kernel<<<2048, 256, 0, stream>>>(d_in[0], xb,  12582912 / 8, flag);
    cvt_bf16_kernel<<<1536, 256, 0, stream>>>(d_in[1], Wqb, 3145728 / 8, flag);
    cvt_bf16_kernel<<<512,  256, 0, stream>>>(d_in[3], Wob, 1048576 / 8, flag);
    rope_table_kernel<<<768 * 512 / 256, 256, 0, stream>>>(tab);

    // QKV GEMM (M=12288, N=3072): 256x256 tiles, natural grid (48,12), fused bias+RoPE
    gemm256p_kernel<<<dim3(48, 12), 512, 0, stream>>>(xb, Wqb, d_in[2], qkv, 3072, flag, 0, tab, 1);
    // Attention: QBLK=128, grid (6, 16, 16), 512 threads
    attn_kernel<<<dim3(6, 16, 16), 512, 0, stream>>>(qkv, y);
    // Output GEMM (M=12288, N=1024): 256x256 tiles, natural grid (48,4)
    gemm256p_kernel<<<dim3(48, 4), 512, 0, stream>>>(y, Wob, d_in[4], d_out, 1024, flag, 1, tab, 0);
}